// Round 8
// baseline (101.014 us; speedup 1.0000x reference)
//
#include <hip/hip_runtime.h>
#include <math.h>

// RoutingCapsules — B=16, I=2048, K=64, J=64, D=32, 3 routing iters.
//   s[b,j,d]  = sum_k W[j,d,k] y[b,j,k],    y[b,j,k]  = sum_i c[b,j,i] x[b,i,k]
//   uv[b,j,i] = sum_k x[b,i,k] wv[b,j,k],   wv[b,j,k] = sum_d W[j,d,k] v[b,j,d]
// Iter-1 c uniform -> y1 = (1/64) sum_i x.  Logits linear in wv -> wv2 = wv1+dwv.
//
// R9 = R8 + phase-homogeneous block mapping. R8 post-mortem: 45.6us invariant
// across two sync designs; VALU accounts for 11us, phases ~26us -> ~20us lost
// in the 5 per-b wait_all hops. Mechanism: with b=bid>>5, co-resident blocks
// (bid, bid+256) belong to DIFFERENT b's at different phases; when both
// compute simultaneously each runs 2x slow, and wait_all takes max over 32
// blocks -> every hop pays the contention tail (~4us x 5). Fix: b=(bid>>4)&15,
// t=(bid&15)|((bid>>8)<<4): co-resident pair is SAME b (256 = 0 mod 8 XCDs,
// 0 mod 32 CUs/XCD) -> always same phase -> deterministic 2-way sharing,
// spread collapses to detection latency.
//
// R7/R8 design (on top of R6's uncached-dwordx4 zero-fence):
//  * caps distributed: block t owns j={2t,2t+1}; wv[j] block-private in REG.
//  * W held in VGPRs (4 float4/thread, loaded once).
//  * sync = per-block flag array (done[b][t] = phase, monotonic 1..5) polled
//    by one coalesced 32-lane uncached gather + __all. No atomics.

#define BB 16
#define II 2048
#define KK 64
#define JJ 64
#define DD 32
#define ITILE 64
#define NT 32              // i-tiles per b; block t of b owns j = {2t, 2t+1}

#define SCRATCH_FLOATS ((KK + JJ) * 68 + 8 * 72)   // 9280 floats = 37120 B

#define PH_YBAR   1
#define PH_CAPS0  2
#define PH_ROUTE1 3
#define PH_CAPS1  4
#define PH_ROUTE2 5

#define SYNC_INTS (BB * 64)    // 32 flags per b, padded to 64 ints (256 B)

typedef float f32x4 __attribute__((ext_vector_type(4)));

// ---- coherent (cache-bypassing) accessors, async; value valid after cohwait0 ----
__device__ __forceinline__ f32x4 cohload4a(const float* p) {
    f32x4 t;
    asm volatile("global_load_dwordx4 %0, %1, off sc0 sc1"
                 : "=&v"(t) : "v"(p) : "memory");
    return t;
}
__device__ __forceinline__ int cohload1ia(const int* p) {
    int t;
    asm volatile("global_load_dword %0, %1, off sc0 sc1"
                 : "=&v"(t) : "v"(p) : "memory");
    return t;
}
__device__ __forceinline__ void cohwait0() {
    asm volatile("s_waitcnt vmcnt(0)" ::: "memory");
    __builtin_amdgcn_sched_barrier(0);   // rule #18: pin uses after the wait
}
__device__ __forceinline__ void cohstore4(float* p, f32x4 v) {
    asm volatile("global_store_dwordx4 %0, %1, off sc0 sc1"
                 :: "v"(p), "v"(v) : "memory");
}
__device__ __forceinline__ void cohstore1(float* p, float v) {
    asm volatile("global_store_dword %0, %1, off sc0 sc1"
                 :: "v"(p), "v"(v) : "memory");
}
__device__ __forceinline__ void cohstore1i(int* p, int v) {
    asm volatile("global_store_dword %0, %1, off sc0 sc1"
                 :: "v"(p), "v"(v) : "memory");
}
__device__ __forceinline__ void cohfence() {   // drain this wave's stores
    asm volatile("s_waitcnt vmcnt(0)" ::: "memory");
}

// flag: done[b][t] = phase (single writer per slot, monotonic)
__device__ __forceinline__ void set_phase(int* slot, int phase) {
    if (threadIdx.x == 0) cohstore1i(slot, phase);
}
// wave-0: one coalesced uncached gather of all 32 flags + __all
__device__ __forceinline__ void wait_all(const int* done_b, int phase) {
    if (threadIdx.x < 64) {
        const int* p = done_b + (threadIdx.x & 31);
        for (;;) {
            int v = cohload1ia(p);
            cohwait0();
            if (__all(v >= phase)) break;
            __builtin_amdgcn_s_sleep(4);
        }
    }
    __syncthreads();
}

// ---------------------------------------------------------------------------
// caps phase: this block's 2 j. W in regs (w0..w3 = W[j0+jr, d, kq4*16..+15]).
//   MODE 0: y = (1/64)*sum_t ybarp[t][k];  wv_reg  = W^T v; store wv
//   MODE 1: y = sum_t ypart[t][j][k];      wv_reg += W^T v; store wv
//   MODE 2: y = sum_t ypart[t][j][k];      out = squash(s)
// Thread map: jr = tid>>7, rem = tid&127, d = rem>>2, kq4 = rem&3.
// ---------------------------------------------------------------------------
template <int MODE>
__device__ __forceinline__ void caps_phase(
    int b, int j0, float4 w0, float4 w1, float4 w2, float4 w3,
    const float* __restrict__ ypb, float* __restrict__ wvb,
    float* __restrict__ out, float* scratch, float& wv_reg) {
    const int tid = threadIdx.x;
    const int wave = tid >> 6, lane = tid & 63;
    const int jr = tid >> 7, rem = tid & 127;

    float* y_sm   = scratch;          // [2][64]
    float* wvp_sm = scratch + 128;    // [2][2][64]
    float* sq_sm  = scratch + 384;    // [2][2]

    // (A) y-reduce: wave w -> j-slot jw=w>>1, k-half=(w&1)*32; lanes: kq8,th
    {
        const int jw = wave >> 1;
        const int khalf = (wave & 1) * 32;
        const int kq8 = lane & 7, th = lane >> 3;
        f32x4 vb[4];
        if (MODE == 0) {
            #pragma unroll
            for (int n = 0; n < 4; ++n)
                vb[n] = cohload4a(ypb + (size_t)(th + n * 8) * KK + khalf + kq8 * 4);
        } else {
            const int jA = j0 + jw;
            #pragma unroll
            for (int n = 0; n < 4; ++n)
                vb[n] = cohload4a(ypb + ((size_t)(th + n * 8) * JJ + jA) * KK + khalf + kq8 * 4);
        }
        cohwait0();
        float a0 = vb[0][0] + vb[1][0] + vb[2][0] + vb[3][0];
        float a1 = vb[0][1] + vb[1][1] + vb[2][1] + vb[3][1];
        float a2 = vb[0][2] + vb[1][2] + vb[2][2] + vb[3][2];
        float a3 = vb[0][3] + vb[1][3] + vb[2][3] + vb[3][3];
        #pragma unroll
        for (int m = 8; m <= 32; m <<= 1) {     // reduce over th (lane bits 3..5)
            a0 += __shfl_xor(a0, m, 64);
            a1 += __shfl_xor(a1, m, 64);
            a2 += __shfl_xor(a2, m, 64);
            a3 += __shfl_xor(a3, m, 64);
        }
        if (MODE == 0) {
            a0 *= (1.f / 64.f); a1 *= (1.f / 64.f);
            a2 *= (1.f / 64.f); a3 *= (1.f / 64.f);
        }
        if (th == 0)
            *(float4*)&y_sm[jw * 64 + khalf + kq8 * 4] = make_float4(a0, a1, a2, a3);
    }
    __syncthreads();

    // (C) s[j,d] = dot(W[j,d,:], y[j,:]) — 4 threads per (j,d), 16 k each
    const int d = rem >> 2, kq4 = rem & 3;
    float sv;
    {
        const float* yb = y_sm + jr * 64 + kq4 * 16;
        const float4 y0 = *(const float4*)(yb + 0);
        const float4 y1 = *(const float4*)(yb + 4);
        const float4 y2 = *(const float4*)(yb + 8);
        const float4 y3 = *(const float4*)(yb + 12);
        sv = w0.x * y0.x + w0.y * y0.y + w0.z * y0.z + w0.w * y0.w
           + w1.x * y1.x + w1.y * y1.y + w1.z * y1.z + w1.w * y1.w
           + w2.x * y2.x + w2.y * y2.y + w2.z * y2.z + w2.w * y2.w
           + w3.x * y3.x + w3.y * y3.y + w3.z * y3.z + w3.w * y3.w;
        sv += __shfl_xor(sv, 1, 64);   // reduce kq4 (lane bits 0..1)
        sv += __shfl_xor(sv, 2, 64);
    }

    // (D) squash: butterfly over lane bits 2..5; each (bit0,bit1) class holds
    // one lane per d -> ps = sum over this wave's 16 d of s^2 (no overcount).
    float ps = sv * sv;
    ps += __shfl_xor(ps, 4, 64);
    ps += __shfl_xor(ps, 8, 64);
    ps += __shfl_xor(ps, 16, 64);
    ps += __shfl_xor(ps, 32, 64);
    if (lane == 0) sq_sm[jr * 2 + (wave & 1)] = ps;
    __syncthreads();
    ps = sq_sm[jr * 2] + sq_sm[jr * 2 + 1];
    const float f = ps / ((1.f + ps) * (sqrtf(ps) + 1e-8f));

    if (MODE == 2) {
        if (kq4 == 0) out[((size_t)b * JJ + j0 + jr) * DD + d] = sv * f;
        return;
    }

    // (E) wv[j,k] = sum_d W[j,d,k] v[j,d]; reduce d via shfl, halves via LDS
    const float vv = sv * f;
    float c[16];
    {
        const float4 ww[4] = {w0, w1, w2, w3};
        #pragma unroll
        for (int q = 0; q < 4; ++q) {
            c[q * 4 + 0] = ww[q].x * vv;
            c[q * 4 + 1] = ww[q].y * vv;
            c[q * 4 + 2] = ww[q].z * vv;
            c[q * 4 + 3] = ww[q].w * vv;
        }
    }
    #pragma unroll
    for (int m = 4; m <= 32; m <<= 1)
        #pragma unroll
        for (int q = 0; q < 16; ++q)
            c[q] += __shfl_xor(c[q], m, 64);
    if (lane < 4) {                    // lane == kq4, d-half sum holder
        float* wp = wvp_sm + jr * 128 + (wave & 1) * 64 + lane * 16;
        #pragma unroll
        for (int q = 0; q < 16; ++q) wp[q] = c[q];
    }
    __syncthreads();
    if (rem < 64) {
        const int k = rem;
        float tot = wvp_sm[jr * 128 + k] + wvp_sm[jr * 128 + 64 + k];
        if (MODE == 1) tot += wv_reg;
        wv_reg = tot;
        cohstore1(&wvb[(size_t)(j0 + jr) * KK + k], tot);
    }
}

// ---------------------------------------------------------------------------
// route pass (unchanged, verified R2-R8): uv = x·wv^T; softmax_j; ypt = c^T x
// ---------------------------------------------------------------------------
__device__ __forceinline__ void route_pass(const float* __restrict__ wvb,
                                           float* __restrict__ ypt,
                                           float (*x_smT)[68], float* scratch) {
    const int tid = threadIdx.x;
    float (*wv_smT)[68] = (float (*)[68])scratch;
    float (*uv_smT)[68] = (float (*)[68])(scratch + KK * 68);
    float (*red)[72]    = (float (*)[72])(scratch + (KK + JJ) * 68);

    {   // stage wv (transposed) — batched async coherent 16B loads
        f32x4 vb[4];
        #pragma unroll
        for (int n = 0; n < 4; ++n)
            vb[n] = cohload4a(wvb + (size_t)(tid + n * 256) * 4);
        cohwait0();
        #pragma unroll
        for (int n = 0; n < 4; ++n) {
            const int idx = tid + n * 256;
            const int jj = idx >> 4, kq = idx & 15;
            wv_smT[kq * 4 + 0][jj] = vb[n][0];
            wv_smT[kq * 4 + 1][jj] = vb[n][1];
            wv_smT[kq * 4 + 2][jj] = vb[n][2];
            wv_smT[kq * 4 + 3][jj] = vb[n][3];
        }
    }
    __syncthreads();

    {   // uv[j][i], 4i x 4j per thread, b128 reads
        const int ib = (tid & 15) * 4, jb = (tid >> 4) * 4;
        float acc[4][4] = {};
        for (int k = 0; k < KK; ++k) {
            const float4 xv = *(const float4*)&x_smT[k][ib];
            const float4 wvv = *(const float4*)&wv_smT[k][jb];
            acc[0][0] += xv.x * wvv.x; acc[0][1] += xv.x * wvv.y;
            acc[0][2] += xv.x * wvv.z; acc[0][3] += xv.x * wvv.w;
            acc[1][0] += xv.y * wvv.x; acc[1][1] += xv.y * wvv.y;
            acc[1][2] += xv.y * wvv.z; acc[1][3] += xv.y * wvv.w;
            acc[2][0] += xv.z * wvv.x; acc[2][1] += xv.z * wvv.y;
            acc[2][2] += xv.z * wvv.z; acc[2][3] += xv.z * wvv.w;
            acc[3][0] += xv.w * wvv.x; acc[3][1] += xv.w * wvv.y;
            acc[3][2] += xv.w * wvv.z; acc[3][3] += xv.w * wvv.w;
        }
        #pragma unroll
        for (int r = 0; r < 4; ++r)
            *(float4*)&uv_smT[jb + r][ib] =
                make_float4(acc[0][r], acc[1][r], acc[2][r], acc[3][r]);
    }
    __syncthreads();

    {   // softmax over j (down columns); 16 values per wave in registers
        const int i = tid & 63;
        const int w = tid >> 6;
        const int j0 = w * 16;
        float e[16];
        float m = -1e30f;
        #pragma unroll
        for (int jj = 0; jj < 16; ++jj) {
            e[jj] = uv_smT[j0 + jj][i];
            m = fmaxf(m, e[jj]);
        }
        red[w][i] = m;
        __syncthreads();
        m = fmaxf(fmaxf(red[0][i], red[1][i]), fmaxf(red[2][i], red[3][i]));
        float s = 0.f;
        #pragma unroll
        for (int jj = 0; jj < 16; ++jj) {
            e[jj] = __expf(e[jj] - m);
            s += e[jj];
        }
        red[4 + w][i] = s;
        __syncthreads();
        const float inv = 1.f / (red[4][i] + red[5][i] + red[6][i] + red[7][i]);
        #pragma unroll
        for (int jj = 0; jj < 16; ++jj) uv_smT[j0 + jj][i] = e[jj] * inv;
    }
    __syncthreads();

    {   // ypt[j][k] = sum_i c[j][i] x[k][i], 4j x 4k per thread, b128 reads
        const int a = tid & 15;
        const int kb = (tid >> 4) * 4;
        float acc[4][4] = {};
        for (int i = 0; i < ITILE; i += 4) {
            float4 xv[4];
            #pragma unroll
            for (int c = 0; c < 4; ++c) xv[c] = *(const float4*)&x_smT[kb + c][i];
            #pragma unroll
            for (int r = 0; r < 4; ++r) {
                const float4 cv = *(const float4*)&uv_smT[a + 16 * r][i];
                #pragma unroll
                for (int c = 0; c < 4; ++c)
                    acc[r][c] += cv.x * xv[c].x + cv.y * xv[c].y +
                                 cv.z * xv[c].z + cv.w * xv[c].w;
            }
        }
        #pragma unroll
        for (int r = 0; r < 4; ++r) {
            f32x4 sv;
            sv[0] = acc[r][0]; sv[1] = acc[r][1]; sv[2] = acc[r][2]; sv[3] = acc[r][3];
            cohstore4(&ypt[(a + 16 * r) * KK + kb], sv);
        }
    }
}

// ---------------------------------------------------------------------------
__global__ __launch_bounds__(256, 2) void fused_kernel(
    const float* __restrict__ x, const float* __restrict__ W,
    float* __restrict__ wv, float* __restrict__ ypart,
    float* __restrict__ out, int* __restrict__ sync) {
    const int bid = blockIdx.x;
    // Phase-homogeneous mapping: co-resident pair (bid, bid+256) -> same b.
    // bid = hi<<8 | mid<<4 | lo  ->  b = mid, t = lo | hi<<4 (bijection).
    const int b = (bid >> 4) & 15;
    const int t = (bid & 15) | ((bid >> 8) << 4);
    const int tid = threadIdx.x;
    const int j0 = 2 * t;

    int* done_b = sync + b * 64;            // 32 flags, 256B-padded per b
    float* wvb = wv + (size_t)b * JJ * KK;
    float* ypb = ypart + (size_t)b * NT * JJ * KK;  // ybar partials overlaid

    __shared__ alignas(16) float x_smT[KK][68];
    __shared__ alignas(16) float scratch[SCRATCH_FLOATS];

    // ---- W -> regs: thread (jr, d=rem>>2, kq4=rem&3) holds 16 k ----
    const int jr = tid >> 7, rem = tid & 127;
    const float* Wp = W + ((size_t)(j0 + jr) * DD + (rem >> 2)) * KK + (rem & 3) * 16;
    const float4 w0 = *(const float4*)(Wp + 0);
    const float4 w1 = *(const float4*)(Wp + 4);
    const float4 w2 = *(const float4*)(Wp + 8);
    const float4 w3 = *(const float4*)(Wp + 12);
    float wv_reg = 0.f;

    // ---- stage x tile (once, reused by ybar + both route passes) ----
    const float4* x4 = (const float4*)(x + ((size_t)b * II + t * ITILE) * KK);
    #pragma unroll
    for (int n = 0; n < 4; ++n) {
        const int idx = tid + n * 256;
        const int i = idx >> 4, kq = idx & 15;
        const float4 v = x4[idx];
        x_smT[kq * 4 + 0][i] = v.x;
        x_smT[kq * 4 + 1][i] = v.y;
        x_smT[kq * 4 + 2][i] = v.z;
        x_smT[kq * 4 + 3][i] = v.w;
    }
    __syncthreads();

    // ---- ybar partial: raw tile sum over 64 i ----
    {
        const int w = tid >> 6, lane = tid & 63;
        const int kk = lane >> 2, q = lane & 3;
        const int k = w * 16 + kk;
        float s = 0.f;
        #pragma unroll
        for (int m = 0; m < 4; ++m) {
            const float4 v = *(const float4*)&x_smT[k][q * 16 + m * 4];
            s += v.x + v.y + v.z + v.w;
        }
        s += __shfl_xor(s, 1, 64);
        s += __shfl_xor(s, 2, 64);
        if (q == 0) cohstore1(&ypb[t * KK + k], s);
    }
    cohfence(); __syncthreads();
    set_phase(done_b + t, PH_YBAR);
    wait_all(done_b, PH_YBAR);

    caps_phase<0>(b, j0, w0, w1, w2, w3, ypb, wvb, out, scratch, wv_reg);
    cohfence(); __syncthreads();
    set_phase(done_b + t, PH_CAPS0);
    wait_all(done_b, PH_CAPS0);

    route_pass(wvb, ypb + (size_t)t * JJ * KK, x_smT, scratch);   // pass 1
    cohfence(); __syncthreads();
    set_phase(done_b + t, PH_ROUTE1);
    wait_all(done_b, PH_ROUTE1);

    caps_phase<1>(b, j0, w0, w1, w2, w3, ypb, wvb, out, scratch, wv_reg);
    cohfence(); __syncthreads();
    set_phase(done_b + t, PH_CAPS1);
    wait_all(done_b, PH_CAPS1);

    route_pass(wvb, ypb + (size_t)t * JJ * KK, x_smT, scratch);   // pass 2
    cohfence(); __syncthreads();
    set_phase(done_b + t, PH_ROUTE2);
    wait_all(done_b, PH_ROUTE2);

    caps_phase<2>(b, j0, w0, w1, w2, w3, ypb, wvb, out, scratch, wv_reg);
}

// ---------------------------------------------------------------------------
// Workspace (floats): wv[65536] | ypart[2097152] | sync[1024 ints = 4KB]
// ybar partials live inside ypart[b] (dead before route1 overwrites them).
// ---------------------------------------------------------------------------
extern "C" void kernel_launch(void* const* d_in, const int* in_sizes, int n_in,
                              void* d_out, int out_size, void* d_ws, size_t ws_size,
                              hipStream_t stream) {
    (void)in_sizes; (void)n_in; (void)out_size; (void)ws_size;
    const float* x = (const float*)d_in[0];
    const float* W = (const float*)d_in[1];
    float* out = (float*)d_out;
    float* ws = (float*)d_ws;

    float* wv = ws;                         // 65536 floats
    float* ypart = ws + 65536;              // 2097152 floats
    int* sync = (int*)(ws + 65536 + 2097152);

    hipMemsetAsync(sync, 0, SYNC_INTS * sizeof(int), stream);
    fused_kernel<<<dim3(BB * NT), dim3(256), 0, stream>>>(x, W, wv, ypart, out, sync);
}

// Round 9
// 82.030 us; speedup vs baseline: 1.2314x; 1.2314x over previous
//
#include <hip/hip_runtime.h>
#include <math.h>

// RoutingCapsules — B=16, I=2048, K=64, J=64, D=32, 3 routing iters.
//   s[b,j,d]  = sum_k W[j,d,k] y[b,j,k],    y[b,j,k]  = sum_i c[b,j,i] x[b,i,k]
//   uv[b,j,i] = sum_k x[b,i,k] wv[b,j,k],   wv[b,j,k] = sum_d W[j,d,k] v[b,j,d]
// Iter-1 c uniform -> y1 = ybar (j-indep). Logits linear in wv -> b3 = x·(wv1+wv2).
//
// R10: revert to the R2 six-kernel skeleton (verified; kernel-boundary sync,
// cached loads) and attack the REAL floor found in R9's post-mortem: the two
// route GEMMs were LDS-BW-bound (~1 GB LDS traffic chip-wide ~ 17-20us, same
// in fused and multi-kernel). Route v2 uses bf16 MFMA (fp32 accumulate):
//  * x staged as bf16 in [i][k] AND [k][i]; wv as [j][k]; 36 KB LDS -> 4 blk/CU
//  * uv via mfma_f32_16x16x32_bf16 (A row=l&15, k-chunk=(l>>4)*8; C col=l&15=j,
//    row=(l>>4)*4+r=i — m89-verified C layout)
//  * softmax fully in-register (per-i row = 16 lanes x 4 regs, shfl_xor 1/2/4/8)
//  * c -> c_bf[j][i] bf16; ypt via second MFMA pair; LDS traffic 8x lower.
// Numerics: W~0.01 -> logits ~2e-3, out ~1e-3; bf16-input rounding with fp32
// accum -> abs error ~1e-5 << 2.07e-3 threshold.
// ybar/caps kernels byte-identical to the R2-verified versions.

#define BB 16
#define II 2048
#define KK 64
#define JJ 64
#define DD 32
#define ITILE 64
#define NT (II / ITILE)   // 32 i-tiles
#define YB 16             // ybar partial chunks

typedef float f32x4 __attribute__((ext_vector_type(4)));
typedef short bf16x8 __attribute__((ext_vector_type(8)));

__device__ __forceinline__ unsigned short f2bf(float f) {   // RNE fp32->bf16
    unsigned int u = __float_as_uint(f);
    u += 0x7FFFu + ((u >> 16) & 1u);
    return (unsigned short)(u >> 16);
}

// ---------------------------------------------------------------------------
// ybar partials (R2 verbatim): ybarp[b][q][k] = (1/64) sum_{i in chunk q} x
// ---------------------------------------------------------------------------
__global__ __launch_bounds__(256) void ybar_kernel(const float* __restrict__ x,
                                                   float* __restrict__ ybarp) {
    const int b = blockIdx.x;
    const int q = blockIdx.y;
    const int tid = threadIdx.x;
    const int kq = tid & 15;
    const int r  = tid >> 4;
    const float4* xp = (const float4*)(x + ((size_t)b * II + (size_t)q * 128) * KK) + kq;
    float4 a = make_float4(0.f, 0.f, 0.f, 0.f);
    #pragma unroll
    for (int n = 0; n < 8; ++n) {
        const float4 v = xp[(size_t)(r + n * 16) * 16];
        a.x += v.x; a.y += v.y; a.z += v.z; a.w += v.w;
    }
    __shared__ float4 sm[16][17];
    sm[r][kq] = a;
    __syncthreads();
    if (tid < 64) {
        const float* smf = (const float*)sm;   // row stride 68 floats
        float s = 0.f;
        #pragma unroll
        for (int rr = 0; rr < 16; ++rr) s += smf[rr * 68 + tid];
        ybarp[(b * YB + q) * KK + tid] = s * (1.0f / 64.0f);
    }
}

// ---------------------------------------------------------------------------
// caps kernel (R2 verbatim): per (b,j): s = W y; v = squash(s);
//   MODE 0: y = sum ybarp (j-indep);  wv  = W^T v
//   MODE 1: y = sum_t ypart;          wv += W^T v
//   MODE 2: y = sum_t ypart;          out = squash(s)
// grid (16,16); 4 waves/block, one j per wave; wave-private LDS.
// ---------------------------------------------------------------------------
template <int MODE>
__global__ __launch_bounds__(256) void caps_kernel(const float* __restrict__ W,
                                                   const float* __restrict__ ybarp,
                                                   const float* __restrict__ ypart,
                                                   float* __restrict__ wv,
                                                   float* __restrict__ out) {
    const int b = blockIdx.x;
    const int jq = blockIdx.y;
    const int tid = threadIdx.x;
    const int w = tid >> 6;
    const int lane = tid & 63;
    const int j = jq * 4 + w;

    __shared__ alignas(16) float W_sm[4][DD][68];
    __shared__ alignas(16) float y_sm[4][KK];
    __shared__ float v_sm[4][DD];

    const float* Wp = W + (size_t)j * DD * KK;
    #pragma unroll
    for (int rr = 0; rr < 8; ++rr) {
        const int idx = rr * 64 + lane;
        const int d = idx >> 4, kq = idx & 15;
        *(float4*)&W_sm[w][d][kq * 4] = *(const float4*)(Wp + d * KK + kq * 4);
    }

    if (MODE == 0) {
        const float* yp = ybarp + (size_t)b * YB * KK + lane;
        float a = 0.f;
        #pragma unroll
        for (int t = 0; t < YB; ++t) a += yp[(size_t)t * KK];
        y_sm[w][lane] = a;
    } else {
        const int kq = lane & 15, th = lane >> 4;
        float4 a = make_float4(0.f, 0.f, 0.f, 0.f);
        #pragma unroll
        for (int n = 0; n < 8; ++n) {
            const int t = th + n * 4;
            const float4 v = *(const float4*)(ypart +
                (((size_t)b * NT + t) * JJ + j) * KK + kq * 4);
            a.x += v.x; a.y += v.y; a.z += v.z; a.w += v.w;
        }
        a.x += __shfl_xor(a.x, 16, 64); a.y += __shfl_xor(a.y, 16, 64);
        a.z += __shfl_xor(a.z, 16, 64); a.w += __shfl_xor(a.w, 16, 64);
        a.x += __shfl_xor(a.x, 32, 64); a.y += __shfl_xor(a.y, 32, 64);
        a.z += __shfl_xor(a.z, 32, 64); a.w += __shfl_xor(a.w, 32, 64);
        if (lane < 16) *(float4*)&y_sm[w][kq * 4] = a;
    }

    const int d = lane & 31;
    const int kh = (lane >> 5) * 32;
    float sv = 0.f;
    #pragma unroll
    for (int kq = 0; kq < 8; ++kq) {
        const float4 wr = *(const float4*)&W_sm[w][d][kh + kq * 4];
        const float4 yr = *(const float4*)&y_sm[w][kh + kq * 4];
        sv += wr.x * yr.x + wr.y * yr.y + wr.z * yr.z + wr.w * yr.w;
    }
    sv += __shfl_xor(sv, 32, 64);

    float ps = sv * sv;
    #pragma unroll
    for (int m = 1; m < 32; m <<= 1) ps += __shfl_xor(ps, m, 64);
    const float f = ps / ((1.f + ps) * (sqrtf(ps) + 1e-8f));

    if (MODE == 2) {
        if (lane < DD) out[((size_t)b * JJ + j) * DD + lane] = sv * f;
    } else {
        if (lane < DD) v_sm[w][lane] = sv * f;
        float a = 0.f;
        #pragma unroll
        for (int dd = 0; dd < DD; ++dd) a += W_sm[w][dd][lane] * v_sm[w][dd];
        const size_t idx = ((size_t)b * JJ + j) * KK + lane;
        if (MODE == 1) a += wv[idx];
        wv[idx] = a;
    }
}

// ---------------------------------------------------------------------------
// route kernel v2 (bf16 MFMA): uv = x·wv^T -> softmax_j (in-register) ->
// ypt[j][k] = sum_i c[j][i] x[i][k]. grid (16,32), 256 thr, 36 KB LDS.
// ---------------------------------------------------------------------------
#define RPAD 72   // bf16 row stride: multiple of 8 -> every 8-elem chunk 16B-aligned

__global__ __launch_bounds__(256, 4) void route_kernel(const float* __restrict__ x,
                                                       const float* __restrict__ wv,
                                                       float* __restrict__ ypart) {
    const int b = blockIdx.x;
    const int t = blockIdx.y;
    const int tid = threadIdx.x;
    const int w = tid >> 6;           // wave
    const int lr = tid & 15;          // lane & 15
    const int lg = (tid >> 4) & 3;    // lane >> 4

    __shared__ unsigned short x_bf[64][RPAD];    // [i][k]
    __shared__ unsigned short xT_bf[64][RPAD];   // [k][i]
    __shared__ unsigned short wv_bf[64][RPAD];   // [j][k]
    __shared__ unsigned short c_bf[64][RPAD];    // [j][i]

    // ---- stage x (both layouts) and wv, converted to bf16 ----
    const float4* x4 = (const float4*)(x + ((size_t)b * II + t * ITILE) * KK);
    #pragma unroll
    for (int n = 0; n < 4; ++n) {
        const int idx = tid + n * 256;
        const int i = idx >> 4, kq = idx & 15;
        const float4 v = x4[idx];
        const unsigned short b0 = f2bf(v.x), b1 = f2bf(v.y),
                             b2 = f2bf(v.z), b3 = f2bf(v.w);
        *(unsigned int*)&x_bf[i][kq * 4 + 0] = (unsigned int)b0 | ((unsigned int)b1 << 16);
        *(unsigned int*)&x_bf[i][kq * 4 + 2] = (unsigned int)b2 | ((unsigned int)b3 << 16);
        xT_bf[kq * 4 + 0][i] = b0;
        xT_bf[kq * 4 + 1][i] = b1;
        xT_bf[kq * 4 + 2][i] = b2;
        xT_bf[kq * 4 + 3][i] = b3;
    }
    const float4* wv4 = (const float4*)(wv + (size_t)b * JJ * KK);
    #pragma unroll
    for (int n = 0; n < 4; ++n) {
        const int idx = tid + n * 256;
        const int j = idx >> 4, kq = idx & 15;
        const float4 v = wv4[idx];
        *(unsigned int*)&wv_bf[j][kq * 4 + 0] =
            (unsigned int)f2bf(v.x) | ((unsigned int)f2bf(v.y) << 16);
        *(unsigned int*)&wv_bf[j][kq * 4 + 2] =
            (unsigned int)f2bf(v.z) | ((unsigned int)f2bf(v.w) << 16);
    }
    __syncthreads();

    // ---- uv via MFMA: wave w owns i-strip [16w,16w+16); 4 j-tiles x K=64 ----
    // A-frag: row = lr (i), k-chunk = lg*8. B-frag: col = lr (j), k-chunk = lg*8.
    // C: col = lr = j-in-tile, row = lg*4 + r = i-in-strip (m89-verified).
    f32x4 acc[4] = {{0,0,0,0},{0,0,0,0},{0,0,0,0},{0,0,0,0}};
    {
        const bf16x8 a0 = *(const bf16x8*)&x_bf[16 * w + lr][lg * 8];
        const bf16x8 a1 = *(const bf16x8*)&x_bf[16 * w + lr][32 + lg * 8];
        #pragma unroll
        for (int jt = 0; jt < 4; ++jt) {
            const bf16x8 bf0 = *(const bf16x8*)&wv_bf[jt * 16 + lr][lg * 8];
            const bf16x8 bf1 = *(const bf16x8*)&wv_bf[jt * 16 + lr][32 + lg * 8];
            acc[jt] = __builtin_amdgcn_mfma_f32_16x16x32_bf16(a0, bf0, acc[jt], 0, 0, 0);
            acc[jt] = __builtin_amdgcn_mfma_f32_16x16x32_bf16(a1, bf1, acc[jt], 0, 0, 0);
        }
    }

    // ---- softmax over j, fully in-register ----
    // lane holds uv[i = 16w + lg*4 + r][j = jt*16 + lr]; row of 64 j lives in
    // 16 lanes (lr) x 4 regs (jt) -> shfl_xor 1/2/4/8 reduces within group.
    float c[4][4];   // [jt][r]
    #pragma unroll
    for (int r = 0; r < 4; ++r) {
        float m = fmaxf(fmaxf(acc[0][r], acc[1][r]), fmaxf(acc[2][r], acc[3][r]));
        m = fmaxf(m, __shfl_xor(m, 1, 64));
        m = fmaxf(m, __shfl_xor(m, 2, 64));
        m = fmaxf(m, __shfl_xor(m, 4, 64));
        m = fmaxf(m, __shfl_xor(m, 8, 64));
        const float e0 = __expf(acc[0][r] - m);
        const float e1 = __expf(acc[1][r] - m);
        const float e2 = __expf(acc[2][r] - m);
        const float e3 = __expf(acc[3][r] - m);
        float s = e0 + e1 + e2 + e3;
        s += __shfl_xor(s, 1, 64);
        s += __shfl_xor(s, 2, 64);
        s += __shfl_xor(s, 4, 64);
        s += __shfl_xor(s, 8, 64);
        const float inv = 1.f / s;
        c[0][r] = e0 * inv; c[1][r] = e1 * inv;
        c[2][r] = e2 * inv; c[3][r] = e3 * inv;
    }

    // ---- c -> c_bf[j][i] bf16, pair-packed along i ----
    #pragma unroll
    for (int jt = 0; jt < 4; ++jt) {
        #pragma unroll
        for (int rp = 0; rp < 2; ++rp) {
            const unsigned int pk = (unsigned int)f2bf(c[jt][rp * 2])
                                  | ((unsigned int)f2bf(c[jt][rp * 2 + 1]) << 16);
            *(unsigned int*)&c_bf[jt * 16 + lr][16 * w + lg * 4 + rp * 2] = pk;
        }
    }
    __syncthreads();

    // ---- ypt via MFMA: wave w owns j-strip [16w,16w+16); 4 k-tiles x K(i)=64 ----
    // A = c_bf[j][i] (row = lr = j, i-chunk = lg*8); B = xT_bf[k][i] (col = lr = k).
    f32x4 acy[4] = {{0,0,0,0},{0,0,0,0},{0,0,0,0},{0,0,0,0}};
    {
        const bf16x8 c0 = *(const bf16x8*)&c_bf[16 * w + lr][lg * 8];
        const bf16x8 c1 = *(const bf16x8*)&c_bf[16 * w + lr][32 + lg * 8];
        #pragma unroll
        for (int kt = 0; kt < 4; ++kt) {
            const bf16x8 xf0 = *(const bf16x8*)&xT_bf[kt * 16 + lr][lg * 8];
            const bf16x8 xf1 = *(const bf16x8*)&xT_bf[kt * 16 + lr][32 + lg * 8];
            acy[kt] = __builtin_amdgcn_mfma_f32_16x16x32_bf16(c0, xf0, acy[kt], 0, 0, 0);
            acy[kt] = __builtin_amdgcn_mfma_f32_16x16x32_bf16(c1, xf1, acy[kt], 0, 0, 0);
        }
    }
    float* yp = ypart + ((size_t)b * NT + t) * JJ * KK;
    #pragma unroll
    for (int kt = 0; kt < 4; ++kt)
        #pragma unroll
        for (int r = 0; r < 4; ++r)
            yp[(16 * w + lg * 4 + r) * KK + kt * 16 + lr] = acy[kt][r];
}

// ---------------------------------------------------------------------------
// Workspace (floats): wv[65536] | ybarp[16384] | ypart[2097152]  (~8.7 MB)
// No memset needed — every buffer fully written before read.
// ---------------------------------------------------------------------------
extern "C" void kernel_launch(void* const* d_in, const int* in_sizes, int n_in,
                              void* d_out, int out_size, void* d_ws, size_t ws_size,
                              hipStream_t stream) {
    (void)in_sizes; (void)n_in; (void)out_size; (void)ws_size;
    const float* x = (const float*)d_in[0];
    const float* W = (const float*)d_in[1];
    float* out = (float*)d_out;
    float* ws = (float*)d_ws;

    float* wv    = ws;                    // 65536
    float* ybarp = ws + 65536;            // 16384
    float* ypart = ws + 65536 + 16384;    // 2097152

    ybar_kernel<<<dim3(BB, YB), 256, 0, stream>>>(x, ybarp);
    caps_kernel<0><<<dim3(BB, 16), 256, 0, stream>>>(W, ybarp, ypart, wv, out); // wv1
    route_kernel<<<dim3(BB, NT), 256, 0, stream>>>(x, wv, ypart);               // c2 -> y2
    caps_kernel<1><<<dim3(BB, 16), 256, 0, stream>>>(W, ybarp, ypart, wv, out); // wv1+wv2
    route_kernel<<<dim3(BB, NT), 256, 0, stream>>>(x, wv, ypart);               // c3 -> y3
    caps_kernel<2><<<dim3(BB, 16), 256, 0, stream>>>(W, ybarp, ypart, wv, out); // out
}

// Round 10
// 81.144 us; speedup vs baseline: 1.2449x; 1.0109x over previous
//
#include <hip/hip_runtime.h>
#include <math.h>

// RoutingCapsules — B=16, I=2048, K=64, J=64, D=32, 3 routing iters.
//   s[b,j,d]  = sum_k W[j,d,k] y[b,j,k],    y[b,j,k]  = sum_i c[b,j,i] x[b,i,k]
//   uv[b,j,i] = sum_k x[b,i,k] wv[b,j,k],   wv[b,j,k] = sum_d W[j,d,k] v[b,j,d]
// Iter-1 c uniform -> y1 = ybar (j-indep). Logits linear in wv -> b3 = x·(wv1+wv2).
//
// R11 = R10 (six-kernel skeleton + bf16-MFMA route, 82us) + traffic halving:
//  * ybar (which already streams all of x) also emits x_bf (bf16, 4 MB);
//    routes read x_bf instead of fp32 x (8->4 MB/pass, no in-route convert;
//    numerically IDENTICAL to R10 — same RNE convert, done once).
//  * ypart stored bf16 (8->4 MB/round-trip x2): route epilogue repacks the
//    accumulators through the dead wv_bf LDS buffer into coalesced 16B
//    stores; caps<1>/<2> read ushort8 rows, accumulate fp32. Adds ~0.2%
//    relative on y -> absmax ~+1e-4 (R10 was 4.9e-4, threshold 2.07e-3).
// R9 retro-diagnosis (journal): fused persistent kernel was coherence-BW
// bound — 33 MB of sc0/sc1 uncached traffic at ~730 GB/s = 46us floor.
// Cached multi-kernel is structurally right on CDNA4 (per-XCD L2, G16).

#define BB 16
#define II 2048
#define KK 64
#define JJ 64
#define DD 32
#define ITILE 64
#define NT (II / ITILE)   // 32 i-tiles
#define YB 16             // ybar partial chunks

typedef float f32x4 __attribute__((ext_vector_type(4)));
typedef short bf16x8 __attribute__((ext_vector_type(8)));
typedef unsigned short u16x4 __attribute__((ext_vector_type(4)));
typedef unsigned short u16x8 __attribute__((ext_vector_type(8)));

__device__ __forceinline__ unsigned short f2bf(float f) {   // RNE fp32->bf16
    unsigned int u = __float_as_uint(f);
    u += 0x7FFFu + ((u >> 16) & 1u);
    return (unsigned short)(u >> 16);
}
__device__ __forceinline__ float bf2f(unsigned short u) {
    return __uint_as_float((unsigned int)u << 16);
}

// ---------------------------------------------------------------------------
// ybar partials + x_bf emission: ybarp[b][q][k] = (1/64) sum_{i in chunk} x;
// x_bf[b][i][k] = bf16(x). grid (16,16), 256 thr.
// ---------------------------------------------------------------------------
__global__ __launch_bounds__(256) void ybar_kernel(const float* __restrict__ x,
                                                   float* __restrict__ ybarp,
                                                   unsigned short* __restrict__ x_bf) {
    const int b = blockIdx.x;
    const int q = blockIdx.y;
    const int tid = threadIdx.x;
    const int kq = tid & 15;
    const int r  = tid >> 4;
    const size_t row0 = (size_t)b * II + (size_t)q * 128;
    const float4* xp = (const float4*)(x + row0 * KK) + kq;
    float4 a = make_float4(0.f, 0.f, 0.f, 0.f);
    #pragma unroll
    for (int n = 0; n < 8; ++n) {
        const int i = r + n * 16;
        const float4 v = xp[(size_t)i * 16];
        a.x += v.x; a.y += v.y; a.z += v.z; a.w += v.w;
        u16x4 bv;
        bv[0] = f2bf(v.x); bv[1] = f2bf(v.y); bv[2] = f2bf(v.z); bv[3] = f2bf(v.w);
        *(u16x4*)&x_bf[(row0 + i) * KK + kq * 4] = bv;
    }
    __shared__ float4 sm[16][17];
    sm[r][kq] = a;
    __syncthreads();
    if (tid < 64) {
        const float* smf = (const float*)sm;   // row stride 68 floats
        float s = 0.f;
        #pragma unroll
        for (int rr = 0; rr < 16; ++rr) s += smf[rr * 68 + tid];
        ybarp[(b * YB + q) * KK + tid] = s * (1.0f / 64.0f);
    }
}

// ---------------------------------------------------------------------------
// caps kernel: per (b,j): s = W y; v = squash(s);
//   MODE 0: y = sum ybarp (fp32, j-indep);  wv  = W^T v
//   MODE 1: y = sum_t ypart_bf (bf16);      wv += W^T v
//   MODE 2: y = sum_t ypart_bf (bf16);      out = squash(s)
// grid (16,16); 4 waves/block, one j per wave; wave-private LDS.
// ---------------------------------------------------------------------------
template <int MODE>
__global__ __launch_bounds__(256) void caps_kernel(const float* __restrict__ W,
                                                   const float* __restrict__ ybarp,
                                                   const unsigned short* __restrict__ ypart_bf,
                                                   float* __restrict__ wv,
                                                   float* __restrict__ out) {
    const int b = blockIdx.x;
    const int jq = blockIdx.y;
    const int tid = threadIdx.x;
    const int w = tid >> 6;
    const int lane = tid & 63;
    const int j = jq * 4 + w;

    __shared__ alignas(16) float W_sm[4][DD][68];
    __shared__ alignas(16) float y_sm[4][KK];
    __shared__ float v_sm[4][DD];

    const float* Wp = W + (size_t)j * DD * KK;
    #pragma unroll
    for (int rr = 0; rr < 8; ++rr) {
        const int idx = rr * 64 + lane;
        const int d = idx >> 4, kq = idx & 15;
        *(float4*)&W_sm[w][d][kq * 4] = *(const float4*)(Wp + d * KK + kq * 4);
    }

    if (MODE == 0) {
        const float* yp = ybarp + (size_t)b * YB * KK + lane;
        float a = 0.f;
        #pragma unroll
        for (int t = 0; t < YB; ++t) a += yp[(size_t)t * KK];
        y_sm[w][lane] = a;
    } else {
        // y[j,k] = sum over 32 bf16 tiles; lanes: kq8 = 8 chunks of 8 k, th = 8 tiles
        const int kq8 = lane & 7, th = lane >> 3;
        float a[8] = {0.f, 0.f, 0.f, 0.f, 0.f, 0.f, 0.f, 0.f};
        #pragma unroll
        for (int n = 0; n < 4; ++n) {
            const int tt = th + n * 8;
            const u16x8 v = *(const u16x8*)(ypart_bf +
                (((size_t)b * NT + tt) * JJ + j) * KK + kq8 * 8);
            #pragma unroll
            for (int m = 0; m < 8; ++m) a[m] += bf2f(v[m]);
        }
        #pragma unroll
        for (int s = 8; s <= 32; s <<= 1) {
            #pragma unroll
            for (int m = 0; m < 8; ++m) a[m] += __shfl_xor(a[m], s, 64);
        }
        if (th == 0) {
            #pragma unroll
            for (int m = 0; m < 8; ++m) y_sm[w][kq8 * 8 + m] = a[m];
        }
    }

    const int d = lane & 31;
    const int kh = (lane >> 5) * 32;
    float sv = 0.f;
    #pragma unroll
    for (int kq = 0; kq < 8; ++kq) {
        const float4 wr = *(const float4*)&W_sm[w][d][kh + kq * 4];
        const float4 yr = *(const float4*)&y_sm[w][kh + kq * 4];
        sv += wr.x * yr.x + wr.y * yr.y + wr.z * yr.z + wr.w * yr.w;
    }
    sv += __shfl_xor(sv, 32, 64);

    float ps = sv * sv;
    #pragma unroll
    for (int m = 1; m < 32; m <<= 1) ps += __shfl_xor(ps, m, 64);
    const float f = ps / ((1.f + ps) * (sqrtf(ps) + 1e-8f));

    if (MODE == 2) {
        if (lane < DD) out[((size_t)b * JJ + j) * DD + lane] = sv * f;
    } else {
        if (lane < DD) v_sm[w][lane] = sv * f;
        float a = 0.f;
        #pragma unroll
        for (int dd = 0; dd < DD; ++dd) a += W_sm[w][dd][lane] * v_sm[w][dd];
        const size_t idx = ((size_t)b * JJ + j) * KK + lane;
        if (MODE == 1) a += wv[idx];
        wv[idx] = a;
    }
}

// ---------------------------------------------------------------------------
// route kernel (bf16 MFMA, bf16 I/O): uv = x·wv^T -> softmax_j (in-register)
// -> ypt_bf[j][k] = bf16( sum_i c[j][i] x[i][k] ). grid (16,32), 36 KB LDS.
// ---------------------------------------------------------------------------
#define RPAD 72   // ushort row stride: 144 B = 9*16 -> every 8-elem chunk 16B-aligned

__global__ __launch_bounds__(256, 4) void route_kernel(const unsigned short* __restrict__ xg_bf,
                                                       const float* __restrict__ wv,
                                                       unsigned short* __restrict__ ypart_bf) {
    const int b = blockIdx.x;
    const int t = blockIdx.y;
    const int tid = threadIdx.x;
    const int w = tid >> 6;           // wave
    const int lr = tid & 15;          // lane & 15
    const int lg = (tid >> 4) & 3;    // lane >> 4

    __shared__ unsigned short x_bf[64][RPAD];    // [i][k]
    __shared__ unsigned short xT_bf[64][RPAD];   // [k][i]
    __shared__ unsigned short wv_bf[64][RPAD];   // [j][k]; reused as ypt pack buffer
    __shared__ unsigned short c_bf[64][RPAD];    // [j][i]

    // ---- stage x tile (bf16 global, both LDS layouts) ----
    const u16x8* xg = (const u16x8*)(xg_bf + ((size_t)b * II + t * ITILE) * KK);
    #pragma unroll
    for (int n = 0; n < 2; ++n) {
        const int idx = tid + n * 256;        // 0..511: 64 i x 8 chunks
        const int i = idx >> 3, ch = idx & 7;
        const u16x8 v = xg[idx];
        *(u16x8*)&x_bf[i][ch * 8] = v;
        #pragma unroll
        for (int m = 0; m < 8; ++m) xT_bf[ch * 8 + m][i] = v[m];
    }
    // ---- stage wv (fp32 -> bf16) ----
    const float4* wv4 = (const float4*)(wv + (size_t)b * JJ * KK);
    #pragma unroll
    for (int n = 0; n < 4; ++n) {
        const int idx = tid + n * 256;
        const int j = idx >> 4, kq = idx & 15;
        const float4 v = wv4[idx];
        *(unsigned int*)&wv_bf[j][kq * 4 + 0] =
            (unsigned int)f2bf(v.x) | ((unsigned int)f2bf(v.y) << 16);
        *(unsigned int*)&wv_bf[j][kq * 4 + 2] =
            (unsigned int)f2bf(v.z) | ((unsigned int)f2bf(v.w) << 16);
    }
    __syncthreads();

    // ---- uv via MFMA: wave w owns i-strip [16w,16w+16); 4 j-tiles x K=64 ----
    f32x4 acc[4] = {{0,0,0,0},{0,0,0,0},{0,0,0,0},{0,0,0,0}};
    {
        const bf16x8 a0 = *(const bf16x8*)&x_bf[16 * w + lr][lg * 8];
        const bf16x8 a1 = *(const bf16x8*)&x_bf[16 * w + lr][32 + lg * 8];
        #pragma unroll
        for (int jt = 0; jt < 4; ++jt) {
            const bf16x8 bf0 = *(const bf16x8*)&wv_bf[jt * 16 + lr][lg * 8];
            const bf16x8 bf1 = *(const bf16x8*)&wv_bf[jt * 16 + lr][32 + lg * 8];
            acc[jt] = __builtin_amdgcn_mfma_f32_16x16x32_bf16(a0, bf0, acc[jt], 0, 0, 0);
            acc[jt] = __builtin_amdgcn_mfma_f32_16x16x32_bf16(a1, bf1, acc[jt], 0, 0, 0);
        }
    }

    // ---- softmax over j, fully in-register (row = 16 lanes x 4 regs) ----
    float c[4][4];   // [jt][r]
    #pragma unroll
    for (int r = 0; r < 4; ++r) {
        float m = fmaxf(fmaxf(acc[0][r], acc[1][r]), fmaxf(acc[2][r], acc[3][r]));
        m = fmaxf(m, __shfl_xor(m, 1, 64));
        m = fmaxf(m, __shfl_xor(m, 2, 64));
        m = fmaxf(m, __shfl_xor(m, 4, 64));
        m = fmaxf(m, __shfl_xor(m, 8, 64));
        const float e0 = __expf(acc[0][r] - m);
        const float e1 = __expf(acc[1][r] - m);
        const float e2 = __expf(acc[2][r] - m);
        const float e3 = __expf(acc[3][r] - m);
        float s = e0 + e1 + e2 + e3;
        s += __shfl_xor(s, 1, 64);
        s += __shfl_xor(s, 2, 64);
        s += __shfl_xor(s, 4, 64);
        s += __shfl_xor(s, 8, 64);
        const float inv = 1.f / s;
        c[0][r] = e0 * inv; c[1][r] = e1 * inv;
        c[2][r] = e2 * inv; c[3][r] = e3 * inv;
    }

    // ---- c -> c_bf[j][i] bf16, pair-packed along i ----
    #pragma unroll
    for (int jt = 0; jt < 4; ++jt) {
        #pragma unroll
        for (int rp = 0; rp < 2; ++rp) {
            const unsigned int pk = (unsigned int)f2bf(c[jt][rp * 2])
                                  | ((unsigned int)f2bf(c[jt][rp * 2 + 1]) << 16);
            *(unsigned int*)&c_bf[jt * 16 + lr][16 * w + lg * 4 + rp * 2] = pk;
        }
    }
    __syncthreads();   // all waves done with uv (wv_bf now dead -> reusable)

    // ---- ypt via MFMA: wave w owns j-strip [16w,16w+16); 4 k-tiles x K(i)=64 ----
    f32x4 acy[4] = {{0,0,0,0},{0,0,0,0},{0,0,0,0},{0,0,0,0}};
    {
        const bf16x8 c0 = *(const bf16x8*)&c_bf[16 * w + lr][lg * 8];
        const bf16x8 c1 = *(const bf16x8*)&c_bf[16 * w + lr][32 + lg * 8];
        #pragma unroll
        for (int kt = 0; kt < 4; ++kt) {
            const bf16x8 xf0 = *(const bf16x8*)&xT_bf[kt * 16 + lr][lg * 8];
            const bf16x8 xf1 = *(const bf16x8*)&xT_bf[kt * 16 + lr][32 + lg * 8];
            acy[kt] = __builtin_amdgcn_mfma_f32_16x16x32_bf16(c0, xf0, acy[kt], 0, 0, 0);
            acy[kt] = __builtin_amdgcn_mfma_f32_16x16x32_bf16(c1, xf1, acy[kt], 0, 0, 0);
        }
    }
    // repack acy (bf16) through wv_bf, then coalesced 16B global stores
    #pragma unroll
    for (int kt = 0; kt < 4; ++kt)
        #pragma unroll
        for (int r = 0; r < 4; ++r)
            wv_bf[16 * w + lg * 4 + r][kt * 16 + lr] = f2bf(acy[kt][r]);
    __syncthreads();
    unsigned short* yp = ypart_bf + ((size_t)b * NT + t) * JJ * KK;
    #pragma unroll
    for (int n = 0; n < 2; ++n) {
        const int idx = tid + n * 256;        // 64 j x 8 chunks
        const int row = idx >> 3, ch = idx & 7;
        *(u16x8*)&yp[row * KK + ch * 8] = *(const u16x8*)&wv_bf[row][ch * 8];
    }
}

// ---------------------------------------------------------------------------
// Workspace (floats): wv[65536] | ybarp[16384] | x_bf[1048576 f-equiv]
//                     | ypart_bf[1048576 f-equiv]   (total 8.7 MB, = R10)
// No memset needed — every buffer fully written before read.
// ---------------------------------------------------------------------------
extern "C" void kernel_launch(void* const* d_in, const int* in_sizes, int n_in,
                              void* d_out, int out_size, void* d_ws, size_t ws_size,
                              hipStream_t stream) {
    (void)in_sizes; (void)n_in; (void)out_size; (void)ws_size;
    const float* x = (const float*)d_in[0];
    const float* W = (const float*)d_in[1];
    float* out = (float*)d_out;
    float* ws = (float*)d_ws;

    float* wv    = ws;                                   // 65536 floats
    float* ybarp = ws + 65536;                           // 16384 floats
    unsigned short* x_bf     = (unsigned short*)(ws + 65536 + 16384);
    unsigned short* ypart_bf = (unsigned short*)(ws + 65536 + 16384 + 1048576);

    ybar_kernel<<<dim3(BB, YB), 256, 0, stream>>>(x, ybarp, x_bf);
    caps_kernel<0><<<dim3(BB, 16), 256, 0, stream>>>(W, ybarp, ypart_bf, wv, out); // wv1
    route_kernel<<<dim3(BB, NT), 256, 0, stream>>>(x_bf, wv, ypart_bf);            // c2 -> y2
    caps_kernel<1><<<dim3(BB, 16), 256, 0, stream>>>(W, ybarp, ypart_bf, wv, out); // wv1+wv2
    route_kernel<<<dim3(BB, NT), 256, 0, stream>>>(x_bf, wv, ypart_bf);            // c3 -> y3
    caps_kernel<2><<<dim3(BB, 16), 256, 0, stream>>>(W, ybarp, ypart_bf, wv, out); // out
}